// Round 14
// baseline (6759.271 us; speedup 1.0000x reference)
//
#include <hip/hip_runtime.h>
#include <hip/hip_bf16.h>

namespace {

constexpr int B = 1024, T = 512, H = 60, G = 180, NTHR = 192;
constexpr int NB = 4;        // batch elements per rec block (grid 256 = 1/CU)
constexpr int GR = 64;       // rows per gi-gemm block
constexpr int PADF4 = 2464;  // gemm LDS ballast (r13 gemm measured 14us; keep identical)

__device__ __forceinline__ float sigm(float x) { return 1.f / (1.f + __expf(-x)); }
__device__ __forceinline__ float tanh_fast(float x) {
  x = fminf(fmaxf(x, -15.f), 15.f);
  const float e = __expf(-2.f * x);
  return (1.f - e) / (1.f + e);
}

// ---------------------------------------------------------------------------
// gi GEMM (unchanged from r13: measured ~14us/dispatch, ~100 TF on its slice).
// ---------------------------------------------------------------------------
__global__ __launch_bounds__(NTHR, 1) void gi_gemm_kernel(
    const float* __restrict__ x,      // chunk base: [row][60] contiguous
    const float* __restrict__ Wih,    // [180][60]
    const float* __restrict__ bih,
    float* __restrict__ gi)           // chunk base: [row][180]
{
  __shared__ __align__(16) float4 smem4[PADF4];
  float* xs = (float*)smem4;
  const int tid = threadIdx.x;
  const size_t row0 = (size_t)blockIdx.x * GR;
  const int rr = (tid < G) ? tid : 0;

  float4 W0, W1, W2, W3, W4, W5, W6, W7, W8, W9, W10, W11, W12, W13, W14;
#define LW(i) W##i = *(const float4*)&Wih[(size_t)rr * H + (i) * 4];
  LW(0) LW(1) LW(2) LW(3) LW(4) LW(5) LW(6) LW(7)
  LW(8) LW(9) LW(10) LW(11) LW(12) LW(13) LW(14)
#undef LW
  const float bi = bih[rr];

  {
    const float4* s4 = (const float4*)(x + row0 * H);
#pragma unroll
    for (int q = 0; q < 5; ++q) smem4[q * NTHR + tid] = s4[q * NTHR + tid];
  }
  __syncthreads();

#define GX(s, a)                                                      \
  {                                                                   \
    const float4 xv = *(const float4*)&xb[(s) * H + 4 * kk];          \
    a = fmaf(w.x, xv.x, a); a = fmaf(w.y, xv.y, a);                   \
    a = fmaf(w.z, xv.z, a); a = fmaf(w.w, xv.w, a);                   \
  }
#define PASS(p)                                                       \
  {                                                                   \
    const float* xb = xs + (p) * 8 * H;                               \
    float a0 = bi, a1 = bi, a2 = bi, a3 = bi;                         \
    float a4 = bi, a5 = bi, a6 = bi, a7 = bi;                         \
    _Pragma("unroll")                                                 \
    for (int kk = 0; kk < 15; ++kk) {                                 \
      float4 w;                                                       \
      switch (kk) {                                                   \
        case 0: w = W0; break;   case 1: w = W1; break;               \
        case 2: w = W2; break;   case 3: w = W3; break;               \
        case 4: w = W4; break;   case 5: w = W5; break;               \
        case 6: w = W6; break;   case 7: w = W7; break;               \
        case 8: w = W8; break;   case 9: w = W9; break;               \
        case 10: w = W10; break; case 11: w = W11; break;             \
        case 12: w = W12; break; case 13: w = W13; break;             \
        default: w = W14; break;                                      \
      }                                                               \
      GX(0, a0) GX(1, a1) GX(2, a2) GX(3, a3)                         \
      GX(4, a4) GX(5, a5) GX(6, a6) GX(7, a7)                         \
    }                                                                 \
    if (tid < G) {                                                    \
      float* o = gi + (row0 + (p) * 8) * G + rr;                      \
      o[0 * G] = a0; o[1 * G] = a1; o[2 * G] = a2; o[3 * G] = a3;     \
      o[4 * G] = a4; o[5 * G] = a5; o[6 * G] = a6; o[7 * G] = a7;     \
    }                                                                 \
  }
  PASS(0) PASS(1) PASS(2) PASS(3) PASS(4) PASS(5) PASS(6) PASS(7)
#undef PASS
#undef GX
}

// ---------------------------------------------------------------------------
// Recurrent GRU chunk, LDS-resident TRANSPOSED weights + NB=4 batch.
// DESIGN PRINCIPLE (r1-r13 lesson): no per-thread state > ~25 VGPR, so the
// allocator's occupancy lottery is irrelevant. Weights are re-read from LDS
// every step BY DESIGN:
//   - wT[k][192]: thread r reads wT[k][r] as b32 -> 64 consecutive lanes on
//     32 banks x2 = conflict-free (2-way aliasing is free, m136).
//   - h_sh[bq][.] read as wave-broadcast float4 (same addr all lanes, free).
//   - 4 batch elems amortize each weight read 4x: per wave/step 60 w-reads +
//     60 h-broadcasts + 240 FMAs -> LDS issue ~ VALU ~ 500 cyc, overlapped.
// ---------------------------------------------------------------------------
template <bool SCALAR_X, bool WRITE_YS, bool WRITE_PRED>
__global__ __launch_bounds__(NTHR, 1) void gru_rec_kernel(
    const float* __restrict__ gi,      // [nsteps][B][180] chunk-local (!SCALAR_X)
    const float* __restrict__ xsc,     // [B][T] (SCALAR_X)
    const float* __restrict__ Wih1,    // [180][1] (SCALAR_X)
    const float* __restrict__ bih1,    // [180] (SCALAR_X)
    const float* __restrict__ Whh, const float* __restrict__ bhh,
    const float* __restrict__ h_in, int h_in_stride,  // null => zeros
    float* __restrict__ ys_out,        // chunk base [nsteps][B][60]
    float* __restrict__ h_out,         // [B][60] carry
    float* __restrict__ enc_out,       // pre-offset slot, stride 180; or null
    float* __restrict__ pred_out,      // [B][T] (WRITE_PRED)
    const float* __restrict__ linW, const float* __restrict__ linb,
    int t0, int nsteps)
{
  __shared__ float wT[H * NTHR];                 // 46.08 KB, wT[k*192 + r]
  __shared__ __align__(16) float h_sh[NB][64];   // h + pad
  __shared__ float gates[NB][4][64];             // Ar,Az,Nn,Hn per batch
  __shared__ float pv[NB][64];
  __shared__ float lw_sh[64];
  __shared__ float xs_seq[NB][T];                // SCALAR_X input (8 KB)

  const int tid = threadIdx.x;
  const int b0 = blockIdx.x * NB;
  const bool rowact = tid < G;
  const int rr = rowact ? tid : 0;

  // ---- stage transposed Whh into LDS (one-time) ----
  for (int i = tid; i < G * H; i += NTHR) {
    const int r = i / H, k = i - r * H;
    wT[k * NTHR + r] = Whh[i];
  }
  // ---- init h ----
  for (int u = tid; u < NB * 64; u += NTHR) {
    const int bq = u >> 6, j = u & 63;
    h_sh[bq][j] = (j < H && h_in) ? h_in[(size_t)(b0 + bq) * h_in_stride + j] : 0.f;
  }
  if (tid < 64) lw_sh[tid] = (WRITE_PRED && tid < H) ? linW[tid] : 0.f;
  if constexpr (SCALAR_X) {
    for (int i = tid; i < NB * nsteps; i += NTHR) {
      const int bq = i / nsteps, s = i - bq * nsteps;
      xs_seq[bq][s] = xsc[(size_t)(b0 + bq) * T + t0 + s];
    }
  }

  const float bh = rowact ? bhh[rr] : 0.f;
  float wih0 = 0.f, bi0 = 0.f;
  if constexpr (SCALAR_X) {
    if (rowact) { wih0 = Wih1[rr]; bi0 = bih1[rr]; }
  }
  float lb = 0.f;
  if constexpr (WRITE_PRED) lb = linb[0];
  __syncthreads();

  const int g = rr / H;
  const int j = rr - g * H;

  // gi prefetch, depth 2
  float ga0 = 0, ga1 = 0, ga2 = 0, ga3 = 0, gb0 = 0, gb1 = 0, gb2 = 0, gb3 = 0;
  if constexpr (!SCALAR_X) {
    if (rowact) {
      ga0 = gi[((size_t)0 * B + b0 + 0) * G + rr];
      ga1 = gi[((size_t)0 * B + b0 + 1) * G + rr];
      ga2 = gi[((size_t)0 * B + b0 + 2) * G + rr];
      ga3 = gi[((size_t)0 * B + b0 + 3) * G + rr];
      if (nsteps > 1) {
        gb0 = gi[((size_t)1 * B + b0 + 0) * G + rr];
        gb1 = gi[((size_t)1 * B + b0 + 1) * G + rr];
        gb2 = gi[((size_t)1 * B + b0 + 2) * G + rr];
        gb3 = gi[((size_t)1 * B + b0 + 3) * G + rr];
      }
    }
  }

  for (int s = 0; s < nsteps; ++s) {
    float gn0 = 0, gn1 = 0, gn2 = 0, gn3 = 0;
    if constexpr (!SCALAR_X) {
      if (rowact && s + 2 < nsteps) {
        gn0 = gi[((size_t)(s + 2) * B + b0 + 0) * G + rr];
        gn1 = gi[((size_t)(s + 2) * B + b0 + 1) * G + rr];
        gn2 = gi[((size_t)(s + 2) * B + b0 + 2) * G + rr];
        gn3 = gi[((size_t)(s + 2) * B + b0 + 3) * G + rr];
      }
    }

    // ---------- dot phase: c[bq] = bh + Whh[r].h[bq] ----------
    if (rowact) {
      float c0 = bh, c1 = bh, c2 = bh, c3 = bh;
#pragma unroll
      for (int k4 = 0; k4 < 15; ++k4) {
        const float4 h0 = *(const float4*)&h_sh[0][k4 * 4];
        const float4 h1 = *(const float4*)&h_sh[1][k4 * 4];
        const float4 h2 = *(const float4*)&h_sh[2][k4 * 4];
        const float4 h3 = *(const float4*)&h_sh[3][k4 * 4];
        const float w0 = wT[(k4 * 4 + 0) * NTHR + rr];
        const float w1 = wT[(k4 * 4 + 1) * NTHR + rr];
        const float w2 = wT[(k4 * 4 + 2) * NTHR + rr];
        const float w3 = wT[(k4 * 4 + 3) * NTHR + rr];
        c0 = fmaf(w0, h0.x, c0); c0 = fmaf(w1, h0.y, c0);
        c0 = fmaf(w2, h0.z, c0); c0 = fmaf(w3, h0.w, c0);
        c1 = fmaf(w0, h1.x, c1); c1 = fmaf(w1, h1.y, c1);
        c1 = fmaf(w2, h1.z, c1); c1 = fmaf(w3, h1.w, c1);
        c2 = fmaf(w0, h2.x, c2); c2 = fmaf(w1, h2.y, c2);
        c2 = fmaf(w2, h2.z, c2); c2 = fmaf(w3, h2.w, c2);
        c3 = fmaf(w0, h3.x, c3); c3 = fmaf(w1, h3.y, c3);
        c3 = fmaf(w2, h3.z, c3); c3 = fmaf(w3, h3.w, c3);
      }
      float av0, av1, av2, av3;
      if constexpr (SCALAR_X) {
        av0 = fmaf(wih0, xs_seq[0][s], bi0);
        av1 = fmaf(wih0, xs_seq[1][s], bi0);
        av2 = fmaf(wih0, xs_seq[2][s], bi0);
        av3 = fmaf(wih0, xs_seq[3][s], bi0);
      } else {
        av0 = ga0; av1 = ga1; av2 = ga2; av3 = ga3;
      }
      if (g == 0) {
        gates[0][0][j] = av0 + c0; gates[1][0][j] = av1 + c1;
        gates[2][0][j] = av2 + c2; gates[3][0][j] = av3 + c3;
      } else if (g == 1) {
        gates[0][1][j] = av0 + c0; gates[1][1][j] = av1 + c1;
        gates[2][1][j] = av2 + c2; gates[3][1][j] = av3 + c3;
      } else {
        gates[0][2][j] = av0; gates[0][3][j] = c0;
        gates[1][2][j] = av1; gates[1][3][j] = c1;
        gates[2][2][j] = av2; gates[2][3][j] = c2;
        gates[3][2][j] = av3; gates[3][3][j] = c3;
      }
    }
    if constexpr (!SCALAR_X) {
      ga0 = gb0; ga1 = gb1; ga2 = gb2; ga3 = gb3;
      gb0 = gn0; gb1 = gn1; gb2 = gn2; gb3 = gn3;
    }
    __syncthreads();

    // ---------- activation phase: 240 units over 192 threads ----------
#pragma unroll
    for (int rep = 0; rep < 2; ++rep) {
      const int u = tid + rep * NTHR;
      if (u < NB * H) {
        const int bq = u / H, jj = u - bq * H;
        const float pr = gates[bq][0][jj];
        const float pz = gates[bq][1][jj];
        const float pa = gates[bq][2][jj];
        const float pc = gates[bq][3][jj];
        const float rg = sigm(pr), zg = sigm(pz);
        const float nv = tanh_fast(fmaf(rg, pc, pa));
        const float hold = h_sh[bq][jj];
        const float hnew = fmaf(zg, hold - nv, nv);
        h_sh[bq][jj] = hnew;
        if constexpr (WRITE_YS)
          ys_out[(size_t)s * B * H + (size_t)(b0 + bq) * H + jj] = hnew;
        if constexpr (WRITE_PRED) pv[bq][jj] = hnew * lw_sh[jj];
      }
    }
    if constexpr (WRITE_PRED) {
      __syncthreads();  // pv complete
      const int wv = tid >> 6, ln = tid & 63;
      {
        float v = (ln < H) ? pv[wv][ln] : 0.f;
#pragma unroll
        for (int o = 32; o; o >>= 1) v += __shfl_xor(v, o);
        if (ln == 0) pred_out[(size_t)(b0 + wv) * T + t0 + s] = v + lb;
      }
      if (wv == 0) {
        float v = (ln < H) ? pv[3][ln] : 0.f;
#pragma unroll
        for (int o = 32; o; o >>= 1) v += __shfl_xor(v, o);
        if (ln == 0) pred_out[(size_t)(b0 + 3) * T + t0 + s] = v + lb;
      }
    }
    __syncthreads();
  }

  // ---- epilogue: h carry + enc ----
  for (int u = tid; u < NB * H; u += NTHR) {
    const int bq = u / H, jj = u - bq * H;
    h_out[(size_t)(b0 + bq) * H + jj] = h_sh[bq][jj];
    if (enc_out) enc_out[(size_t)(b0 + bq) * G + jj] = h_sh[bq][jj];
  }
}

// ---------------------------------------------------------------------------
// Layer runners (r13 structure: vec layer = nch x (gemm chunk -> rec chunk);
// rec overwrites the ys chunk the gemm consumed; scalar layer = 1 dispatch).
// ---------------------------------------------------------------------------
template <bool WRITE_YS, bool WRITE_PRED>
void run_vec_layer(const float* Wih, const float* bih,
                   const float* Whh, const float* bhh,
                   const float* h_init_slot, float* enc_slot_out,
                   float* ysA, float* gic, float* hio,
                   float* pred, const float* linW, const float* linb,
                   int nch, hipStream_t stream) {
  const int tn = T / nch;
  for (int c = 0; c < nch; ++c) {
    const int t0 = c * tn;
    gi_gemm_kernel<<<dim3((tn * B) / GR), dim3(NTHR), 0, stream>>>(
        ysA + (size_t)t0 * B * H, Wih, bih, gic);
    gru_rec_kernel<false, WRITE_YS, WRITE_PRED>
        <<<dim3(B / NB), dim3(NTHR), 0, stream>>>(
        gic, nullptr, nullptr, nullptr, Whh, bhh,
        c ? hio : h_init_slot, c ? H : G,
        ysA + (size_t)t0 * B * H, hio,
        (c == nch - 1) ? enc_slot_out : nullptr,
        pred, linW, linb, t0, tn);
  }
}

void run_scalar_layer(const float* xsc,
                      const float* Wih, const float* bih,
                      const float* Whh, const float* bhh,
                      const float* h_init_slot, float* enc_slot_out,
                      float* ysA, float* hio, hipStream_t stream) {
  gru_rec_kernel<true, true, false><<<dim3(B / NB), dim3(NTHR), 0, stream>>>(
      nullptr, xsc, Wih, bih, Whh, bhh,
      h_init_slot, G, ysA, hio, enc_slot_out,
      nullptr, nullptr, nullptr, 0, T);
}

}  // namespace

extern "C" void kernel_launch(void* const* d_in, const int* in_sizes, int n_in,
                              void* d_out, int out_size, void* d_ws, size_t ws_size,
                              hipStream_t stream) {
  const float* inputs  = (const float*)d_in[0];
  const float* outputs = (const float*)d_in[1];
  const float* eW_ih0 = (const float*)d_in[2];  const float* eW_hh0 = (const float*)d_in[3];
  const float* eb_ih0 = (const float*)d_in[4];  const float* eb_hh0 = (const float*)d_in[5];
  const float* eW_ih1 = (const float*)d_in[6];  const float* eW_hh1 = (const float*)d_in[7];
  const float* eb_ih1 = (const float*)d_in[8];  const float* eb_hh1 = (const float*)d_in[9];
  const float* eW_ih2 = (const float*)d_in[10]; const float* eW_hh2 = (const float*)d_in[11];
  const float* eb_ih2 = (const float*)d_in[12]; const float* eb_hh2 = (const float*)d_in[13];
  const float* c1_Wih = (const float*)d_in[14]; const float* c1_Whh = (const float*)d_in[15];
  const float* c1_bih = (const float*)d_in[16]; const float* c1_bhh = (const float*)d_in[17];
  const float* c2_Wih = (const float*)d_in[18]; const float* c2_Whh = (const float*)d_in[19];
  const float* c2_bih = (const float*)d_in[20]; const float* c2_bhh = (const float*)d_in[21];
  const float* c3_Wih = (const float*)d_in[22]; const float* c3_Whh = (const float*)d_in[23];
  const float* c3_bih = (const float*)d_in[24]; const float* c3_bhh = (const float*)d_in[25];
  const float* lin_W  = (const float*)d_in[26]; const float* lin_b  = (const float*)d_in[27];

  float* pred = (float*)d_out;                 // [B][T]
  float* enc  = pred + (size_t)B * T;          // [B][3][60]

  const size_t seq = (size_t)T * B * H;        // ys elements

  int nch = 64;
  for (int c : {1, 2, 4, 8, 16, 32}) {
    const size_t need = seq * 4 + (size_t)(T / c) * B * G * 4 + (size_t)B * H * 4;
    if (ws_size >= need) { nch = c; break; }
  }

  float* ysA = (float*)d_ws;                        // [T][B][60] fp32
  float* gic = ysA + seq;                           // [(T/nch)][B][180] fp32
  float* hio = gic + (size_t)(T / nch) * B * G;     // [B][60] fp32

  // ---- encoder ----
  run_scalar_layer(inputs, eW_ih0, eb_ih0, eW_hh0, eb_hh0,
                   nullptr, enc + 0, ysA, hio, stream);
  run_vec_layer<true, false>(eW_ih1, eb_ih1, eW_hh1, eb_hh1,
                             nullptr, enc + 60,
                             ysA, gic, hio, pred, lin_W, lin_b, nch, stream);
  run_vec_layer<false, false>(eW_ih2, eb_ih2, eW_hh2, eb_hh2,
                              nullptr, enc + 120,
                              ysA, gic, hio, pred, lin_W, lin_b, nch, stream);

  // ---- decoder: h1<-enc[2], h2<-enc[1], h3<-enc[0] ----
  run_scalar_layer(outputs, c1_Wih, c1_bih, c1_Whh, c1_bhh,
                   enc + 120, nullptr, ysA, hio, stream);
  run_vec_layer<true, false>(c2_Wih, c2_bih, c2_Whh, c2_bhh,
                             enc + 60, nullptr,
                             ysA, gic, hio, pred, lin_W, lin_b, nch, stream);
  run_vec_layer<false, true>(c3_Wih, c3_bih, c3_Whh, c3_bhh,
                             enc + 0, nullptr,
                             ysA, gic, hio, pred, lin_W, lin_b, nch, stream);
}

// Round 15
// 5706.137 us; speedup vs baseline: 1.1846x; 1.1846x over previous
//
#include <hip/hip_runtime.h>
#include <hip/hip_bf16.h>

namespace {

constexpr int B = 1024, T = 512, H = 60, G = 180, NTHR = 192;
constexpr int GR = 64;       // rows per gi-gemm block
constexpr int PADF4 = 2464;  // gemm LDS ballast (proven 14us config, unchanged)
constexpr int RECF = 9984;   // rec LDS floats = 39936 B -> exactly 4 blocks/CU @384thr

__device__ __forceinline__ float sigm(float x) { return 1.f / (1.f + __expf(-x)); }
__device__ __forceinline__ float tanh_fast(float x) {
  x = fminf(fmaxf(x, -15.f), 15.f);
  const float e = __expf(-2.f * x);
  return (1.f - e) / (1.f + e);
}

// ---------------------------------------------------------------------------
// gi GEMM (unchanged, proven ~14us/dispatch).
// ---------------------------------------------------------------------------
__global__ __launch_bounds__(NTHR, 1) void gi_gemm_kernel(
    const float* __restrict__ x, const float* __restrict__ Wih,
    const float* __restrict__ bih, float* __restrict__ gi) {
  __shared__ __align__(16) float4 smem4[PADF4];
  float* xs = (float*)smem4;
  const int tid = threadIdx.x;
  const size_t row0 = (size_t)blockIdx.x * GR;
  const int rr = (tid < G) ? tid : 0;

  float4 W0, W1, W2, W3, W4, W5, W6, W7, W8, W9, W10, W11, W12, W13, W14;
#define LW(i) W##i = *(const float4*)&Wih[(size_t)rr * H + (i) * 4];
  LW(0) LW(1) LW(2) LW(3) LW(4) LW(5) LW(6) LW(7)
  LW(8) LW(9) LW(10) LW(11) LW(12) LW(13) LW(14)
#undef LW
  const float bi = bih[rr];

  {
    const float4* s4 = (const float4*)(x + row0 * H);
#pragma unroll
    for (int q = 0; q < 5; ++q) smem4[q * NTHR + tid] = s4[q * NTHR + tid];
  }
  __syncthreads();

#define GX(s, a)                                                      \
  {                                                                   \
    const float4 xv = *(const float4*)&xb[(s) * H + 4 * kk];          \
    a = fmaf(w.x, xv.x, a); a = fmaf(w.y, xv.y, a);                   \
    a = fmaf(w.z, xv.z, a); a = fmaf(w.w, xv.w, a);                   \
  }
#define PASS(p)                                                       \
  {                                                                   \
    const float* xb = xs + (p) * 8 * H;                               \
    float a0 = bi, a1 = bi, a2 = bi, a3 = bi;                         \
    float a4 = bi, a5 = bi, a6 = bi, a7 = bi;                         \
    _Pragma("unroll")                                                 \
    for (int kk = 0; kk < 15; ++kk) {                                 \
      float4 w;                                                       \
      switch (kk) {                                                   \
        case 0: w = W0; break;   case 1: w = W1; break;               \
        case 2: w = W2; break;   case 3: w = W3; break;               \
        case 4: w = W4; break;   case 5: w = W5; break;               \
        case 6: w = W6; break;   case 7: w = W7; break;               \
        case 8: w = W8; break;   case 9: w = W9; break;               \
        case 10: w = W10; break; case 11: w = W11; break;             \
        case 12: w = W12; break; case 13: w = W13; break;             \
        default: w = W14; break;                                      \
      }                                                               \
      GX(0, a0) GX(1, a1) GX(2, a2) GX(3, a3)                         \
      GX(4, a4) GX(5, a5) GX(6, a6) GX(7, a7)                        \
    }                                                                 \
    if (tid < G) {                                                    \
      float* o = gi + (row0 + (p) * 8) * G + rr;                      \
      o[0 * G] = a0; o[1 * G] = a1; o[2 * G] = a2; o[3 * G] = a3;     \
      o[4 * G] = a4; o[5 * G] = a5; o[6 * G] = a6; o[7 * G] = a7;     \
    }                                                                 \
  }
  PASS(0) PASS(1) PASS(2) PASS(3) PASS(4) PASS(5) PASS(6) PASS(7)
#undef PASS
#undef GX
}

// ---------------------------------------------------------------------------
// Recurrent GRU chunk, SPLIT threads per gate-row (SPLIT=2: 32 wt floats/thr,
// needs ~55 VGPR; SPLIT=4: 16 wt floats/thr, needs ~36 -- safe at the worst
// observed allocator grant of 40). Partial dots combined via shfl_xor within
// consecutive lanes (same wave). 39.9KB LDS ballast caps occupancy at 4
// blocks/CU (384thr) -> regalloc budget 512/6=85 VGPR; observed grants at
// >=38KB LDS were 68/88/132 (r13/r14/r8), all >= the SPLIT=2 need.
// Host selects SPLIT at launch via hipFuncGetAttributes (numRegs >= 56 ->
// weights resident -> use SPLIT=2; else fall back to SPLIT=4).
// ---------------------------------------------------------------------------
template <int SPLIT, bool SCALAR_X, bool WRITE_YS, bool WRITE_PRED>
__global__ __launch_bounds__(((180 * SPLIT + 63) / 64) * 64, 1)
void gru_rec_kernel(
    const float* __restrict__ gi,      // [nsteps][B][180] chunk-local (!SCALAR_X)
    const float* __restrict__ xsc,     // [B][T] (SCALAR_X)
    const float* __restrict__ Wih1,    // [180][1] (SCALAR_X)
    const float* __restrict__ bih1,    // [180] (SCALAR_X)
    const float* __restrict__ Whh, const float* __restrict__ bhh,
    const float* __restrict__ h_in, int h_in_stride,  // null => zeros
    float* __restrict__ ys_out,        // chunk base [nsteps][B][60]
    float* __restrict__ h_out,         // [B][60] carry
    float* __restrict__ enc_out,       // pre-offset slot, stride 180; or null
    float* __restrict__ pred_out,      // [B][T] (WRITE_PRED)
    const float* __restrict__ linW, const float* __restrict__ linb,
    int t0, int nsteps)
{
  constexpr int NT = ((180 * SPLIT + 63) / 64) * 64;
  __shared__ __align__(16) float sm[RECF];   // 39936 B: used region + ballast
  float* h_sh   = sm;          // 64
  float* Ar     = sm + 64;     // 60
  float* Az     = sm + 128;    // 60
  float* Nn     = sm + 192;    // 60
  float* Hn     = sm + 256;    // 60
  float* pv     = sm + 320;    // 64
  float* xs_seq = sm + 384;    // 512

  const int tid = threadIdx.x;
  const int b = blockIdx.x;

  const bool act = tid < G * SPLIT;
  const int row = act ? tid / SPLIT : 0;
  const int part = tid % SPLIT;
  // part's column block: SPLIT=2 -> {0,28}; SPLIT=4 -> {0,16,32,44}; last
  // part loads 4-back and zeroes its first float4 (overlap trick, r12-proven)
  const int hb = (SPLIT == 2) ? part * 7 : part * 4 - (part == 3 ? 1 : 0);
  const int coloff = hb * 4;
  const bool zfirst = (part == SPLIT - 1) && (part != 0);

  float4 W0, W1, W2, W3, W4, W5, W6, W7;
#define LWx(i) W##i = *(const float4*)&Whh[(size_t)row * H + coloff + (i) * 4];
  LWx(0) LWx(1) LWx(2) LWx(3)
  if constexpr (SPLIT == 2) { LWx(4) LWx(5) LWx(6) LWx(7) }
  else { W4 = W5 = W6 = W7 = make_float4(0, 0, 0, 0); }
#undef LWx
  if (zfirst) W0 = make_float4(0.f, 0.f, 0.f, 0.f);
  const float bh = (part == 0) ? bhh[row] : 0.f;

  float wih0 = 0.f, bi0 = 0.f;
  if constexpr (SCALAR_X) {
    if (part == 0) { wih0 = Wih1[row]; bi0 = bih1[row]; }
  }
  float linw = 0.f, lb = 0.f;
  if constexpr (WRITE_PRED) {
    linw = (tid < H) ? linW[tid] : 0.f;
    lb = linb[0];
  }

  if (tid < 64) h_sh[tid] = (tid < H && h_in) ? h_in[(size_t)b * h_in_stride + tid] : 0.f;
  if constexpr (SCALAR_X) {
    for (int i = tid; i < nsteps; i += NT) xs_seq[i] = xsc[(size_t)b * T + t0 + i];
  }
  __syncthreads();

  const int g = row / H;
  const int j = row - g * H;

  // gi prefetch, depth 4, on part-0 lanes (nsteps >= 8 always)
  float g0 = 0.f, g1 = 0.f, g2 = 0.f, g3 = 0.f;
  if constexpr (!SCALAR_X) {
    if (act && part == 0) {
      g0 = gi[((size_t)0 * B + b) * G + row];
      g1 = gi[((size_t)1 * B + b) * G + row];
      g2 = gi[((size_t)2 * B + b) * G + row];
      g3 = gi[((size_t)3 * B + b) * G + row];
    }
  }

  for (int s = 0; s < nsteps; ++s) {
    float gn = 0.f;
    if constexpr (!SCALAR_X) {
      if (act && part == 0 && s + 4 < nsteps)
        gn = gi[((size_t)(s + 4) * B + b) * G + row];
    }

    // ---------- dot phase ----------
    if (act) {
      const float4* h4 = (const float4*)h_sh;
      float c0 = bh, c1 = 0.f;
#define HC(i, d) { const float4 hv = h4[hb + (i)];                    \
        d = fmaf(W##i.x, hv.x, d); d = fmaf(W##i.y, hv.y, d);         \
        d = fmaf(W##i.z, hv.z, d); d = fmaf(W##i.w, hv.w, d); }
      HC(0, c0) HC(1, c1) HC(2, c0) HC(3, c1)
      if constexpr (SPLIT == 2) { HC(4, c0) HC(5, c1) HC(6, c0) HC(7, c1) }
#undef HC
      float c = c0 + c1;
      c += __shfl_xor(c, 1);
      if constexpr (SPLIT == 4) c += __shfl_xor(c, 2);
      if (part == 0) {
        float a;
        if constexpr (SCALAR_X) a = fmaf(wih0, xs_seq[s], bi0);
        else                    a = g0;
        if (g == 0)       Ar[j] = a + c;
        else if (g == 1)  Az[j] = a + c;
        else            { Nn[j] = a; Hn[j] = c; }
      }
    }
    if constexpr (!SCALAR_X) { g0 = g1; g1 = g2; g2 = g3; g3 = gn; }
    __syncthreads();

    // ---------- activation phase ----------
    if (tid < H) {
      const float rg = sigm(Ar[tid]);
      const float zg = sigm(Az[tid]);
      const float nv = tanh_fast(fmaf(rg, Hn[tid], Nn[tid]));
      const float hnew = fmaf(zg, h_sh[tid] - nv, nv);
      h_sh[tid] = hnew;
      if constexpr (WRITE_YS)
        ys_out[(size_t)s * B * H + (size_t)b * H + tid] = hnew;
      if constexpr (WRITE_PRED) pv[tid] = hnew * linw;
    }
    __syncthreads();

    if constexpr (WRITE_PRED) {
      if (tid < 64) {
        float v = (tid < H) ? pv[tid] : 0.f;
#pragma unroll
        for (int o = 32; o; o >>= 1) v += __shfl_xor(v, o);
        if (tid == 0) pred_out[(size_t)b * T + t0 + s] = v + lb;
      }
    }
  }

  if (tid < H) {
    h_out[(size_t)b * H + tid] = h_sh[tid];
    if (enc_out) enc_out[(size_t)b * G + tid] = h_sh[tid];
  }
}

// ---------------------------------------------------------------------------
// Host-side SPLIT selection: query the compiled SPLIT=2 variant's VGPR count
// (host-only API, graph-capture-safe, deterministic). >=56 regs => the
// 32-float weight set is resident => use it; else the 16-float SPLIT=4.
// ---------------------------------------------------------------------------
template <bool SX, bool YS, bool PRED>
void launch_rec(const float* gi, const float* xsc,
                const float* Wih1, const float* bih1,
                const float* Whh, const float* bhh,
                const float* h_in, int h_stride,
                float* ys, float* h_out, float* enc_out, float* pred_out,
                const float* linW, const float* linb, int t0, int nsteps,
                hipStream_t stream) {
  hipFuncAttributes a{};
  int split = 4;
  if (hipFuncGetAttributes(&a, reinterpret_cast<const void*>(
          &gru_rec_kernel<2, SX, YS, PRED>)) == hipSuccess &&
      a.numRegs >= 56)
    split = 2;
  if (split == 2) {
    gru_rec_kernel<2, SX, YS, PRED><<<dim3(B), dim3(384), 0, stream>>>(
        gi, xsc, Wih1, bih1, Whh, bhh, h_in, h_stride,
        ys, h_out, enc_out, pred_out, linW, linb, t0, nsteps);
  } else {
    gru_rec_kernel<4, SX, YS, PRED><<<dim3(B), dim3(768), 0, stream>>>(
        gi, xsc, Wih1, bih1, Whh, bhh, h_in, h_stride,
        ys, h_out, enc_out, pred_out, linW, linb, t0, nsteps);
  }
}

template <bool WRITE_YS, bool WRITE_PRED>
void run_vec_layer(const float* Wih, const float* bih,
                   const float* Whh, const float* bhh,
                   const float* h_init_slot, float* enc_slot_out,
                   float* ysA, float* gic, float* hio,
                   float* pred, const float* linW, const float* linb,
                   int nch, hipStream_t stream) {
  const int tn = T / nch;
  for (int c = 0; c < nch; ++c) {
    const int t0 = c * tn;
    gi_gemm_kernel<<<dim3((tn * B) / GR), dim3(NTHR), 0, stream>>>(
        ysA + (size_t)t0 * B * H, Wih, bih, gic);
    launch_rec<false, WRITE_YS, WRITE_PRED>(
        gic, nullptr, nullptr, nullptr, Whh, bhh,
        c ? hio : h_init_slot, c ? H : G,
        ysA + (size_t)t0 * B * H, hio,
        (c == nch - 1) ? enc_slot_out : nullptr,
        pred, linW, linb, t0, tn, stream);
  }
}

void run_scalar_layer(const float* xsc,
                      const float* Wih, const float* bih,
                      const float* Whh, const float* bhh,
                      const float* h_init_slot, float* enc_slot_out,
                      float* ysA, float* hio, hipStream_t stream) {
  launch_rec<true, true, false>(
      nullptr, xsc, Wih, bih, Whh, bhh, h_init_slot, G,
      ysA, hio, enc_slot_out, nullptr, nullptr, nullptr, 0, T, stream);
}

}  // namespace

extern "C" void kernel_launch(void* const* d_in, const int* in_sizes, int n_in,
                              void* d_out, int out_size, void* d_ws, size_t ws_size,
                              hipStream_t stream) {
  const float* inputs  = (const float*)d_in[0];
  const float* outputs = (const float*)d_in[1];
  const float* eW_ih0 = (const float*)d_in[2];  const float* eW_hh0 = (const float*)d_in[3];
  const float* eb_ih0 = (const float*)d_in[4];  const float* eb_hh0 = (const float*)d_in[5];
  const float* eW_ih1 = (const float*)d_in[6];  const float* eW_hh1 = (const float*)d_in[7];
  const float* eb_ih1 = (const float*)d_in[8];  const float* eb_hh1 = (const float*)d_in[9];
  const float* eW_ih2 = (const float*)d_in[10]; const float* eW_hh2 = (const float*)d_in[11];
  const float* eb_ih2 = (const float*)d_in[12]; const float* eb_hh2 = (const float*)d_in[13];
  const float* c1_Wih = (const float*)d_in[14]; const float* c1_Whh = (const float*)d_in[15];
  const float* c1_bih = (const float*)d_in[16]; const float* c1_bhh = (const float*)d_in[17];
  const float* c2_Wih = (const float*)d_in[18]; const float* c2_Whh = (const float*)d_in[19];
  const float* c2_bih = (const float*)d_in[20]; const float* c2_bhh = (const float*)d_in[21];
  const float* c3_Wih = (const float*)d_in[22]; const float* c3_Whh = (const float*)d_in[23];
  const float* c3_bih = (const float*)d_in[24]; const float* c3_bhh = (const float*)d_in[25];
  const float* lin_W  = (const float*)d_in[26]; const float* lin_b  = (const float*)d_in[27];

  float* pred = (float*)d_out;                 // [B][T]
  float* enc  = pred + (size_t)B * T;          // [B][3][60]

  const size_t seq = (size_t)T * B * H;        // ys elements

  int nch = 64;
  for (int c : {1, 2, 4, 8, 16, 32}) {
    const size_t need = seq * 4 + (size_t)(T / c) * B * G * 4 + (size_t)B * H * 4;
    if (ws_size >= need) { nch = c; break; }
  }

  float* ysA = (float*)d_ws;                        // [T][B][60] fp32
  float* gic = ysA + seq;                           // [(T/nch)][B][180] fp32
  float* hio = gic + (size_t)(T / nch) * B * G;     // [B][60] fp32

  // ---- encoder ----
  run_scalar_layer(inputs, eW_ih0, eb_ih0, eW_hh0, eb_hh0,
                   nullptr, enc + 0, ysA, hio, stream);
  run_vec_layer<true, false>(eW_ih1, eb_ih1, eW_hh1, eb_hh1,
                             nullptr, enc + 60,
                             ysA, gic, hio, pred, lin_W, lin_b, nch, stream);
  run_vec_layer<false, false>(eW_ih2, eb_ih2, eW_hh2, eb_hh2,
                              nullptr, enc + 120,
                              ysA, gic, hio, pred, lin_W, lin_b, nch, stream);

  // ---- decoder: h1<-enc[2], h2<-enc[1], h3<-enc[0] ----
  run_scalar_layer(outputs, c1_Wih, c1_bih, c1_Whh, c1_bhh,
                   enc + 120, nullptr, ysA, hio, stream);
  run_vec_layer<true, false>(c2_Wih, c2_bih, c2_Whh, c2_bhh,
                             enc + 60, nullptr,
                             ysA, gic, hio, pred, lin_W, lin_b, nch, stream);
  run_vec_layer<false, true>(c3_Wih, c3_bih, c3_Whh, c3_bhh,
                             enc + 0, nullptr,
                             ysA, gic, hio, pred, lin_W, lin_b, nch, stream);
}

// Round 16
// 4508.685 us; speedup vs baseline: 1.4992x; 1.2656x over previous
//
#include <hip/hip_runtime.h>
#include <hip/hip_bf16.h>

namespace {

constexpr int B = 1024, T = 512, H = 60, G = 180, NTHR = 192;
constexpr int GR = 64;       // rows per gi-gemm block
constexpr int PADF4 = 2464;  // gemm LDS ballast (proven 14us config, unchanged)
constexpr int NB = 4;        // batch elems per rec block; grid 256 = 1 block/CU
constexpr int NTR = 384;     // rec threads: (row 0..179) x (half 0..1), 6 waves

__device__ __forceinline__ float sigm(float x) { return 1.f / (1.f + __expf(-x)); }
__device__ __forceinline__ float tanh_fast(float x) {
  x = fminf(fmaxf(x, -15.f), 15.f);
  const float e = __expf(-2.f * x);
  return (1.f - e) / (1.f + e);
}

// ---------------------------------------------------------------------------
// gi GEMM (byte-identical to r13/r15: measured ~14us/dispatch).
// ---------------------------------------------------------------------------
__global__ __launch_bounds__(NTHR, 1) void gi_gemm_kernel(
    const float* __restrict__ x, const float* __restrict__ Wih,
    const float* __restrict__ bih, float* __restrict__ gi) {
  __shared__ __align__(16) float4 smem4[PADF4];
  float* xs = (float*)smem4;
  const int tid = threadIdx.x;
  const size_t row0 = (size_t)blockIdx.x * GR;
  const int rr = (tid < G) ? tid : 0;

  float4 W0, W1, W2, W3, W4, W5, W6, W7, W8, W9, W10, W11, W12, W13, W14;
#define LW(i) W##i = *(const float4*)&Wih[(size_t)rr * H + (i) * 4];
  LW(0) LW(1) LW(2) LW(3) LW(4) LW(5) LW(6) LW(7)
  LW(8) LW(9) LW(10) LW(11) LW(12) LW(13) LW(14)
#undef LW
  const float bi = bih[rr];

  {
    const float4* s4 = (const float4*)(x + row0 * H);
#pragma unroll
    for (int q = 0; q < 5; ++q) smem4[q * NTHR + tid] = s4[q * NTHR + tid];
  }
  __syncthreads();

#define GX(s, a)                                                      \
  {                                                                   \
    const float4 xv = *(const float4*)&xb[(s) * H + 4 * kk];          \
    a = fmaf(w.x, xv.x, a); a = fmaf(w.y, xv.y, a);                   \
    a = fmaf(w.z, xv.z, a); a = fmaf(w.w, xv.w, a);                   \
  }
#define PASS(p)                                                       \
  {                                                                   \
    const float* xb = xs + (p) * 8 * H;                               \
    float a0 = bi, a1 = bi, a2 = bi, a3 = bi;                         \
    float a4 = bi, a5 = bi, a6 = bi, a7 = bi;                         \
    _Pragma("unroll")                                                 \
    for (int kk = 0; kk < 15; ++kk) {                                 \
      float4 w;                                                       \
      switch (kk) {                                                   \
        case 0: w = W0; break;   case 1: w = W1; break;               \
        case 2: w = W2; break;   case 3: w = W3; break;               \
        case 4: w = W4; break;   case 5: w = W5; break;               \
        case 6: w = W6; break;   case 7: w = W7; break;               \
        case 8: w = W8; break;   case 9: w = W9; break;               \
        case 10: w = W10; break; case 11: w = W11; break;             \
        case 12: w = W12; break; case 13: w = W13; break;             \
        default: w = W14; break;                                      \
      }                                                               \
      GX(0, a0) GX(1, a1) GX(2, a2) GX(3, a3)                         \
      GX(4, a4) GX(5, a5) GX(6, a6) GX(7, a7)                        \
    }                                                                 \
    if (tid < G) {                                                    \
      float* o = gi + (row0 + (p) * 8) * G + rr;                      \
      o[0 * G] = a0; o[1 * G] = a1; o[2 * G] = a2; o[3 * G] = a3;     \
      o[4 * G] = a4; o[5 * G] = a5; o[6 * G] = a6; o[7 * G] = a7;     \
    }                                                                 \
  }
  PASS(0) PASS(1) PASS(2) PASS(3) PASS(4) PASS(5) PASS(6) PASS(7)
#undef PASS
#undef GX
}

// ---------------------------------------------------------------------------
// Recurrent GRU chunk — LDS-resident weights, NB=4 batch, (row,half) threads.
// NO register-residency assumption (r1-r15 lesson: uncontrollable lottery):
//  - Whh in LDS, row-stride 68 floats. Thread (row,half) reads 8 float4s
//    (half0: f4 0..7 = k0..31; half1: f4 8..15 = k32..63, k60..67 zero-pad).
//    f4-group = (17*row + 8*half + j) mod 8 -> pairs of lanes alias 2-way =
//    free (m136). Per-CU weight traffic 43KB/step / 128B/cyc ~ 340cyc ~ VALU.
//  - h broadcast-read (2 distinct addrs/wave = free). 4 batch dots/thread
//    amortize each weight read 4x. Pair partials combined via shfl_xor(1);
//    both lanes keep the sum and each writes gates for 2 batch elements.
//  - Thread state ~30 VGPR; LDS reads can't be hoisted across barriers,
//    global weight loads are gone from the loop: nothing to sink or spill.
// ---------------------------------------------------------------------------
template <bool SCALAR_X, bool WRITE_YS, bool WRITE_PRED>
__global__ __launch_bounds__(NTR, 1) void gru_rec_kernel(
    const float* __restrict__ gi,      // [nsteps][B][180] chunk-local (!SCALAR_X)
    const float* __restrict__ xsc,     // [B][T] (SCALAR_X)
    const float* __restrict__ Wih1,    // [180][1] (SCALAR_X)
    const float* __restrict__ bih1,    // [180] (SCALAR_X)
    const float* __restrict__ Whh, const float* __restrict__ bhh,
    const float* __restrict__ h_in, int h_in_stride,  // null => zeros
    float* __restrict__ ys_out,        // chunk base [nsteps][B][60]
    float* __restrict__ h_out,         // [B][60] carry
    float* __restrict__ enc_out,       // pre-offset slot, stride 180; or null
    float* __restrict__ pred_out,      // [B][T] (WRITE_PRED)
    const float* __restrict__ linW, const float* __restrict__ linb,
    int t0, int nsteps)
{
  __shared__ __align__(16) float wW[G * 68];     // 48.96 KB, zero-padded cols
  __shared__ __align__(16) float h_sh[NB][64];   // h + zero pad (60..63)
  __shared__ float gates[NB][4][64];             // r,z,n_i,n_h
  __shared__ float pv[NB][64];
  __shared__ float xs[NB][T];                    // SCALAR_X input (8 KB)

  const int tid = threadIdx.x;
  const int b0 = blockIdx.x * NB;
  const bool act = tid < 2 * G;
  const int row = act ? (tid >> 1) : 0;
  const int half = tid & 1;

  // ---- stage weights (conflict-free: consecutive lanes -> consecutive k) --
  for (int i = tid; i < G * H; i += NTR) {
    const int r = i / H, k = i - r * H;
    wW[r * 68 + k] = Whh[i];
  }
  for (int i = tid; i < G * 8; i += NTR) {       // zero pad k=60..67
    const int r = i >> 3, k = H + (i & 7);
    wW[r * 68 + k] = 0.f;
  }
  // ---- init h (pad 60..63 = 0, never written) ----
  for (int i = tid; i < NB * 64; i += NTR) {
    const int q = i >> 6, j = i & 63;
    h_sh[q][j] = (j < H && h_in) ? h_in[(size_t)(b0 + q) * h_in_stride + j] : 0.f;
  }
  if constexpr (SCALAR_X) {
    for (int i = tid; i < NB * nsteps; i += NTR) {
      const int q = i / nsteps, s = i - q * nsteps;
      xs[q][s] = xsc[(size_t)(b0 + q) * T + t0 + s];
    }
  }
  const float bh = bhh[row];
  float wih0 = 0.f, bi0 = 0.f;
  if constexpr (SCALAR_X) { wih0 = Wih1[row]; bi0 = bih1[row]; }
  float linw = 0.f, lb = 0.f;
  if constexpr (WRITE_PRED) {
    lb = linb[0];
    if (tid < NB * H) linw = linW[tid % H];
  }
  __syncthreads();

  const int g = row / H;
  const int jj = row - g * H;
  const int base = half * 8;        // f4 base within the row
  const int myb = 2 * half;         // this lane writes batches myb, myb+1

  // gi prefetch, depth 2 (each lane streams its 2 batch elements)
  float gA0 = 0, gA1 = 0, gB0 = 0, gB1 = 0;
  if constexpr (!SCALAR_X) {
    if (act) {
      gA0 = gi[((size_t)0 * B + b0 + myb + 0) * G + row];
      gA1 = gi[((size_t)0 * B + b0 + myb + 1) * G + row];
      gB0 = gi[((size_t)1 * B + b0 + myb + 0) * G + row];
      gB1 = gi[((size_t)1 * B + b0 + myb + 1) * G + row];
    }
  }

  for (int s = 0; s < nsteps; ++s) {
    float gN0 = 0, gN1 = 0;
    if constexpr (!SCALAR_X) {
      if (act && s + 2 < nsteps) {
        gN0 = gi[((size_t)(s + 2) * B + b0 + myb + 0) * G + row];
        gN1 = gi[((size_t)(s + 2) * B + b0 + myb + 1) * G + row];
      }
    }

    // ---------- dot phase ----------
    if (act) {
      const float4* w4 = (const float4*)&wW[row * 68] + base;
      const float4* h40 = (const float4*)&h_sh[0][0] + base;
      const float4* h41 = (const float4*)&h_sh[1][0] + base;
      const float4* h42 = (const float4*)&h_sh[2][0] + base;
      const float4* h43 = (const float4*)&h_sh[3][0] + base;
      float c0 = 0.f, c1 = 0.f, c2 = 0.f, c3 = 0.f;
#pragma unroll
      for (int j = 0; j < 8; ++j) {
        const float4 w = w4[j];
        const float4 a0 = h40[j];
        const float4 a1 = h41[j];
        const float4 a2 = h42[j];
        const float4 a3 = h43[j];
        c0 = fmaf(w.x, a0.x, c0); c0 = fmaf(w.y, a0.y, c0);
        c0 = fmaf(w.z, a0.z, c0); c0 = fmaf(w.w, a0.w, c0);
        c1 = fmaf(w.x, a1.x, c1); c1 = fmaf(w.y, a1.y, c1);
        c1 = fmaf(w.z, a1.z, c1); c1 = fmaf(w.w, a1.w, c1);
        c2 = fmaf(w.x, a2.x, c2); c2 = fmaf(w.y, a2.y, c2);
        c2 = fmaf(w.z, a2.z, c2); c2 = fmaf(w.w, a2.w, c2);
        c3 = fmaf(w.x, a3.x, c3); c3 = fmaf(w.y, a3.y, c3);
        c3 = fmaf(w.z, a3.z, c3); c3 = fmaf(w.w, a3.w, c3);
      }
      c0 += __shfl_xor(c0, 1);
      c1 += __shfl_xor(c1, 1);
      c2 += __shfl_xor(c2, 1);
      c3 += __shfl_xor(c3, 1);
      const float cc0 = (half ? c2 : c0) + bh;   // full dot for batch myb
      const float cc1 = (half ? c3 : c1) + bh;   // full dot for batch myb+1
      float av0, av1;
      if constexpr (SCALAR_X) {
        av0 = fmaf(wih0, xs[myb + 0][s], bi0);
        av1 = fmaf(wih0, xs[myb + 1][s], bi0);
      } else {
        av0 = gA0; av1 = gA1;
      }
      if (g == 0) {
        gates[myb + 0][0][jj] = av0 + cc0;
        gates[myb + 1][0][jj] = av1 + cc1;
      } else if (g == 1) {
        gates[myb + 0][1][jj] = av0 + cc0;
        gates[myb + 1][1][jj] = av1 + cc1;
      } else {
        gates[myb + 0][2][jj] = av0; gates[myb + 0][3][jj] = cc0;
        gates[myb + 1][2][jj] = av1; gates[myb + 1][3][jj] = cc1;
      }
    }
    if constexpr (!SCALAR_X) { gA0 = gB0; gA1 = gB1; gB0 = gN0; gB1 = gN1; }
    __syncthreads();

    // ---------- activation phase (240 units over 384 threads) ----------
    if (tid < NB * H) {
      const int q = tid / H, j = tid - q * H;
      const float pr = gates[q][0][j];
      const float pz = gates[q][1][j];
      const float pa = gates[q][2][j];
      const float pc = gates[q][3][j];
      const float rg = sigm(pr), zg = sigm(pz);
      const float nv = tanh_fast(fmaf(rg, pc, pa));
      const float hnew = fmaf(zg, h_sh[q][j] - nv, nv);
      h_sh[q][j] = hnew;
      if constexpr (WRITE_YS)
        ys_out[(size_t)s * B * H + (size_t)(b0 + q) * H + j] = hnew;
      if constexpr (WRITE_PRED) pv[q][j] = hnew * linw;
    }
    __syncthreads();

    if constexpr (WRITE_PRED) {
      const int wv = tid >> 6, ln = tid & 63;
      if (wv < NB) {
        float v = (ln < H) ? pv[wv][ln] : 0.f;
#pragma unroll
        for (int o = 32; o; o >>= 1) v += __shfl_xor(v, o);
        if (ln == 0) pred_out[(size_t)(b0 + wv) * T + t0 + s] = v + lb;
      }
      __syncthreads();
    }
  }

  // ---- epilogue: h carry + enc ----
  if (tid < NB * H) {
    const int q = tid / H, j = tid - q * H;
    h_out[(size_t)(b0 + q) * H + j] = h_sh[q][j];
    if (enc_out) enc_out[(size_t)(b0 + q) * G + j] = h_sh[q][j];
  }
}

// ---------------------------------------------------------------------------
// Layer runners: vec layer = nch x (gemm chunk -> rec chunk), gi/ys chunks
// stay L3-resident; scalar layer = one rec dispatch over all T.
// ---------------------------------------------------------------------------
template <bool WRITE_YS, bool WRITE_PRED>
void run_vec_layer(const float* Wih, const float* bih,
                   const float* Whh, const float* bhh,
                   const float* h_init_slot, float* enc_slot_out,
                   float* ysA, float* gic, float* hio,
                   float* pred, const float* linW, const float* linb,
                   int nch, hipStream_t stream) {
  const int tn = T / nch;
  for (int c = 0; c < nch; ++c) {
    const int t0 = c * tn;
    gi_gemm_kernel<<<dim3((tn * B) / GR), dim3(NTHR), 0, stream>>>(
        ysA + (size_t)t0 * B * H, Wih, bih, gic);
    gru_rec_kernel<false, WRITE_YS, WRITE_PRED>
        <<<dim3(B / NB), dim3(NTR), 0, stream>>>(
        gic, nullptr, nullptr, nullptr, Whh, bhh,
        c ? hio : h_init_slot, c ? H : G,
        ysA + (size_t)t0 * B * H, hio,
        (c == nch - 1) ? enc_slot_out : nullptr,
        pred, linW, linb, t0, tn);
  }
}

void run_scalar_layer(const float* xsc,
                      const float* Wih, const float* bih,
                      const float* Whh, const float* bhh,
                      const float* h_init_slot, float* enc_slot_out,
                      float* ysA, float* hio, hipStream_t stream) {
  gru_rec_kernel<true, true, false><<<dim3(B / NB), dim3(NTR), 0, stream>>>(
      nullptr, xsc, Wih, bih, Whh, bhh,
      h_init_slot, G, ysA, hio, enc_slot_out,
      nullptr, nullptr, nullptr, 0, T);
}

}  // namespace

extern "C" void kernel_launch(void* const* d_in, const int* in_sizes, int n_in,
                              void* d_out, int out_size, void* d_ws, size_t ws_size,
                              hipStream_t stream) {
  const float* inputs  = (const float*)d_in[0];
  const float* outputs = (const float*)d_in[1];
  const float* eW_ih0 = (const float*)d_in[2];  const float* eW_hh0 = (const float*)d_in[3];
  const float* eb_ih0 = (const float*)d_in[4];  const float* eb_hh0 = (const float*)d_in[5];
  const float* eW_ih1 = (const float*)d_in[6];  const float* eW_hh1 = (const float*)d_in[7];
  const float* eb_ih1 = (const float*)d_in[8];  const float* eb_hh1 = (const float*)d_in[9];
  const float* eW_ih2 = (const float*)d_in[10]; const float* eW_hh2 = (const float*)d_in[11];
  const float* eb_ih2 = (const float*)d_in[12]; const float* eb_hh2 = (const float*)d_in[13];
  const float* c1_Wih = (const float*)d_in[14]; const float* c1_Whh = (const float*)d_in[15];
  const float* c1_bih = (const float*)d_in[16]; const float* c1_bhh = (const float*)d_in[17];
  const float* c2_Wih = (const float*)d_in[18]; const float* c2_Whh = (const float*)d_in[19];
  const float* c2_bih = (const float*)d_in[20]; const float* c2_bhh = (const float*)d_in[21];
  const float* c3_Wih = (const float*)d_in[22]; const float* c3_Whh = (const float*)d_in[23];
  const float* c3_bih = (const float*)d_in[24]; const float* c3_bhh = (const float*)d_in[25];
  const float* lin_W  = (const float*)d_in[26]; const float* lin_b  = (const float*)d_in[27];

  float* pred = (float*)d_out;                 // [B][T]
  float* enc  = pred + (size_t)B * T;          // [B][3][60]

  const size_t seq = (size_t)T * B * H;        // ys elements

  int nch = 64;
  for (int c : {1, 2, 4, 8, 16, 32}) {
    const size_t need = seq * 4 + (size_t)(T / c) * B * G * 4 + (size_t)B * H * 4;
    if (ws_size >= need) { nch = c; break; }
  }

  float* ysA = (float*)d_ws;                        // [T][B][60] fp32
  float* gic = ysA + seq;                           // [(T/nch)][B][180] fp32
  float* hio = gic + (size_t)(T / nch) * B * G;     // [B][60] fp32

  // ---- encoder ----
  run_scalar_layer(inputs, eW_ih0, eb_ih0, eW_hh0, eb_hh0,
                   nullptr, enc + 0, ysA, hio, stream);
  run_vec_layer<true, false>(eW_ih1, eb_ih1, eW_hh1, eb_hh1,
                             nullptr, enc + 60,
                             ysA, gic, hio, pred, lin_W, lin_b, nch, stream);
  run_vec_layer<false, false>(eW_ih2, eb_ih2, eW_hh2, eb_hh2,
                              nullptr, enc + 120,
                              ysA, gic, hio, pred, lin_W, lin_b, nch, stream);

  // ---- decoder: h1<-enc[2], h2<-enc[1], h3<-enc[0] ----
  run_scalar_layer(outputs, c1_Wih, c1_bih, c1_Whh, c1_bhh,
                   enc + 120, nullptr, ysA, hio, stream);
  run_vec_layer<true, false>(c2_Wih, c2_bih, c2_Whh, c2_bhh,
                             enc + 60, nullptr,
                             ysA, gic, hio, pred, lin_W, lin_b, nch, stream);
  run_vec_layer<false, true>(c3_Wih, c3_bih, c3_Whh, c3_bhh,
                             enc + 0, nullptr,
                             ysA, gic, hio, pred, lin_W, lin_b, nch, stream);
}